// Round 13
// baseline (61.339 us; speedup 1.0000x reference)
//
#include <hip/hip_runtime.h>
#include <hip/hip_bf16.h>

// InfoNCE loss, N=4096, D=256, tau=0.5.
// loss = (1/2n)[ sum_r log(sum_{k!=r} exp(2*Z_r.Z_k)) - 2*sum_i 2*(xn_i.yn_i) ]
// Z = concat(xn, yn) row-normalized; scores in [-2,2] -> no running max needed.
// 2/tau*log2(e) folded into A-side bf16 fragments; epilogue = exp2 + add.
//
// R13 = R12's triangle symmetry with ZERO extra LDS (R5/R12 lesson: 2 blocks/
// CU requires LDS <= 65536 B exactly; R12's +4KB colpart -> 1 block/CU and
// the symmetry gain vanished). Col-side partials now live in REGISTERS
// (ccol[8][4], static indices via full unroll of the 8-tile loop); cross-wave
// reduction happens once post-loop by reusing the then-dead staging buffer as
// scratch; 1 global atomic per column per block.

#define NROWS 8192
#define DDIM  256
#define BM    128        // rows per block = 8 waves * 16 rows
#define BN    64         // cols per LDS tile (32 KB)
#define COLS_PER 512     // cols per block
#define NT (COLS_PER / BN)   // 8 tiles
#define NBLK 544         // sum_{J=0}^{15} (64 - 4J)

typedef __attribute__((ext_vector_type(8))) __bf16 bf16x8_t;
typedef __attribute__((ext_vector_type(4))) float  f32x4_t;

typedef __attribute__((address_space(1))) const void* as1_cvp;
typedef __attribute__((address_space(3))) void*       as3_vp;

#if __has_builtin(__builtin_amdgcn_exp2f)
#define EXP2F __builtin_amdgcn_exp2f
#else
#define EXP2F exp2f
#endif

#define TWO_LOG2E 2.8853900817779268f

// ---- K1: normalize rows + per-pair diag dot + zero rowsum ----
__global__ __launch_bounds__(256) void normalize_diag_kernel(
    const float* __restrict__ x, const float* __restrict__ y,
    __hip_bfloat16* __restrict__ zb, float* __restrict__ rowdiag,
    float* __restrict__ rowsum) {
  const int g = blockIdx.x * 256 + threadIdx.x;
  if (g < NROWS) rowsum[g] = 0.f;

  const int w = threadIdx.x >> 6, lane = threadIdx.x & 63;
  const int i = blockIdx.x * 4 + w;           // 0..4095
  const float4 xv = ((const float4*)(x + (size_t)i * DDIM))[lane];
  const float4 yv = ((const float4*)(y + (size_t)i * DDIM))[lane];
  float ssx = xv.x * xv.x + xv.y * xv.y + xv.z * xv.z + xv.w * xv.w;
  float ssy = yv.x * yv.x + yv.y * yv.y + yv.z * yv.z + yv.w * yv.w;
  float sxy = xv.x * yv.x + xv.y * yv.y + xv.z * yv.z + xv.w * yv.w;
  #pragma unroll
  for (int off = 32; off > 0; off >>= 1) {
    ssx += __shfl_xor(ssx, off, 64);
    ssy += __shfl_xor(ssy, off, 64);
    sxy += __shfl_xor(sxy, off, 64);
  }
  const float sclx = 1.0f / fmaxf(sqrtf(ssx), 1e-8f);
  const float scly = 1.0f / fmaxf(sqrtf(ssy), 1e-8f);
  __hip_bfloat16 px[4], py[4];
  px[0] = __float2bfloat16(xv.x * sclx); px[1] = __float2bfloat16(xv.y * sclx);
  px[2] = __float2bfloat16(xv.z * sclx); px[3] = __float2bfloat16(xv.w * sclx);
  py[0] = __float2bfloat16(yv.x * scly); py[1] = __float2bfloat16(yv.y * scly);
  py[2] = __float2bfloat16(yv.z * scly); py[3] = __float2bfloat16(yv.w * scly);
  *(short4*)(zb + (size_t)i * DDIM + lane * 4)            = *(short4*)px;
  *(short4*)(zb + (size_t)(i + 4096) * DDIM + lane * 4)   = *(short4*)py;
  if (lane == 0) rowdiag[i] = 2.0f * sxy * sclx * scly;   // target score (f32)
}

// ---- K2: strictly-lower-triangle Gram + two-sided sum of exp ----
__global__ __launch_bounds__(512) void gram_lse_kernel(
    const __hip_bfloat16* __restrict__ zbh, float* __restrict__ rowsum) {
  __shared__ short smem[2][BN * DDIM];     // exactly 64 KB, NO other LDS

  const short* zs = (const short*)zbh;
  const char* zbytes = (const char*)zs;
  const int tid  = threadIdx.x;
  const int w    = tid >> 6;    // 0..7
  const int lane = tid & 63;
  const int lhi  = lane >> 4;   // 0..3
  const int llo  = lane & 15;   // 0..15

  // Block -> (J, I) over the strictly-lower triangle. Col chunk J (512 wide),
  // row tile I (128 tall); included iff I >= 4J; count per J = 64 - 4J.
  int jj = 0, rem = blockIdx.x;
  while (rem >= 64 - 4 * jj) { rem -= 64 - 4 * jj; ++jj; }
  const int I = 4 * jj + rem;
  const int i0 = I * BM;
  const int c0 = jj * COLS_PER;
  const bool straddle = (rem <= 3);   // diagonal crosses this block

  // A fragments: 16 rows per wave, full K=256, pre-scaled by bf16(2*log2e).
  const int arow = i0 + w * 16 + llo;
  const float TBF = __bfloat162float(__float2bfloat16(TWO_LOG2E));
  bf16x8_t afrag[8];
  #pragma unroll
  for (int ks = 0; ks < 8; ++ks) {
    afrag[ks] = *(const bf16x8_t*)(zs + (size_t)arow * DDIM + ks * 32 + lhi * 8);
    #pragma unroll
    for (int e = 0; e < 8; ++e)
      afrag[ks][e] = (__bf16)((float)afrag[ks][e] * TBF);
  }

  // Staging offsets (exactly R3): 512 thr x 16 B x 4 = 32 KB tile; linear LDS
  // dest, XOR-swizzle on the global source.
  int soff[4], loff[4];
  #pragma unroll
  for (int it = 0; it < 4; ++it) {
    const int o    = it * 8192 + tid * 16;
    const int cr   = o >> 9;            // 0..63
    const int slot = (o >> 4) & 31;
    soff[it] = cr * 512 + ((slot ^ (cr & 31)) << 4);
    loff[it] = it * 8192 + w * 1024;    // wave-uniform dest base
  }

#define STAGE(buf, ct_) do {                                                  \
    const size_t cbase = (size_t)(c0 + (ct_) * BN) * 512;                     \
    _Pragma("unroll")                                                         \
    for (int it = 0; it < 4; ++it) {                                          \
      __builtin_amdgcn_global_load_lds(                                       \
          (as1_cvp)(zbytes + cbase + (size_t)soff[it]),                       \
          (as3_vp)((char*)smem[buf] + loff[it]), 16, 0, 0);                   \
    }                                                                         \
  } while (0)

  float racc[4] = {0.f, 0.f, 0.f, 0.f};
  float ccol[NT][4];                      // col partials, STATIC indices only
  #pragma unroll
  for (int c = 0; c < NT; ++c)
    #pragma unroll
    for (int n = 0; n < 4; ++n) ccol[c][n] = 0.f;
  const int gr0 = i0 + w * 16 + lhi * 4;  // C/D row = (lane>>4)*4 + j

  STAGE(0, 0);
  asm volatile("s_waitcnt vmcnt(0)" ::: "memory");
  __syncthreads();

  #pragma unroll
  for (int ct = 0; ct < NT; ++ct) {       // FULL unroll: ccol indices static
    if (ct + 1 < NT) STAGE((ct + 1) & 1, ct + 1);   // prefetch overlaps compute
    const int cb = c0 + ct * BN;

    #pragma unroll
    for (int nt = 0; nt < 4; ++nt) {
      const int cr = nt * 16 + llo;      // key (column) this lane feeds as B
      f32x4_t acc = {0.f, 0.f, 0.f, 0.f};
      #pragma unroll
      for (int ks = 0; ks < 8; ++ks) {
        const int kg = ks * 4 + lhi;     // 16B k-slot
        const bf16x8_t bfrag = *(const bf16x8_t*)(
            (const char*)smem[ct & 1] + cr * 512 + ((kg ^ (cr & 31)) << 4));
        acc = __builtin_amdgcn_mfma_f32_16x16x32_bf16(afrag[ks], bfrag, acc, 0, 0, 0);
      }
      float e[4];
      #pragma unroll
      for (int j = 0; j < 4; ++j) e[j] = EXP2F(acc[j]);
      if (straddle) {                    // keep strictly-lower only (kills diag)
        const int gc = cb + cr;
        #pragma unroll
        for (int j = 0; j < 4; ++j) e[j] = ((gr0 + j) > gc) ? e[j] : 0.f;
      }
      #pragma unroll
      for (int j = 0; j < 4; ++j) racc[j] += e[j];       // row side
      // col side: this fragment's 4 rows, then across the wave's 4 lhi groups.
      float cs = (e[0] + e[1]) + (e[2] + e[3]);
      cs += __shfl_xor(cs, 16, 64);
      cs += __shfl_xor(cs, 32, 64);
      ccol[ct][nt] += cs;                // meaningful on lanes<16 (lhi==0)
    }
    asm volatile("s_waitcnt vmcnt(0)" ::: "memory");  // prefetched tile landed
    __syncthreads();
  }
#undef STAGE

  // Row-side flush: reduce across the 16 lanes holding each row's columns.
  #pragma unroll
  for (int j = 0; j < 4; ++j) {
    float v = racc[j];
    v += __shfl_xor(v, 1, 16);
    v += __shfl_xor(v, 2, 16);
    v += __shfl_xor(v, 4, 16);
    v += __shfl_xor(v, 8, 16);
    if (llo == 0) atomicAdd(&rowsum[gr0 + j], v);
  }

  // Col-side flush: staging buffers are dead now -> reuse as scratch.
  // scratch[w][col 0..511]; then 512 threads sum the 8 wave-partials each.
  float* scratch = (float*)smem;          // 16 KB of the 64 KB
  if (lane < 16) {
    #pragma unroll
    for (int c = 0; c < NT; ++c)
      #pragma unroll
      for (int n = 0; n < 4; ++n)
        scratch[w * COLS_PER + c * BN + n * 16 + llo] = ccol[c][n];
  }
  __syncthreads();
  {
    float s = 0.f;
    #pragma unroll
    for (int ww = 0; ww < 8; ++ww) s += scratch[ww * COLS_PER + tid];
    atomicAdd(&rowsum[c0 + tid], s);
  }
}

// ------- K3: loss = (sum_r log(rowsum_r) - 2*sum_i rowdiag_i) / 2n -------
__global__ __launch_bounds__(256) void finalize_kernel(
    const float* __restrict__ rowsum, const float* __restrict__ rowdiag,
    float* __restrict__ out) {
  const int t = threadIdx.x;
  float s = 0.f;
  for (int r4 = t; r4 < NROWS / 4; r4 += 256) {
    const float4 v = ((const float4*)rowsum)[r4];
    s += __logf(v.x) + __logf(v.y) + __logf(v.z) + __logf(v.w);
  }
  for (int i4 = t; i4 < 4096 / 4; i4 += 256) {
    const float4 d = ((const float4*)rowdiag)[i4];
    s -= 2.0f * (d.x + d.y + d.z + d.w);
  }
  #pragma unroll
  for (int off = 32; off > 0; off >>= 1) s += __shfl_xor(s, off, 64);
  __shared__ float wsum[4];
  const int w = t >> 6, lane = t & 63;
  if (lane == 0) wsum[w] = s;
  __syncthreads();
  if (t == 0) out[0] = (wsum[0] + wsum[1] + wsum[2] + wsum[3]) / (float)NROWS;
}

extern "C" void kernel_launch(void* const* d_in, const int* in_sizes, int n_in,
                              void* d_out, int out_size, void* d_ws, size_t ws_size,
                              hipStream_t stream) {
  const float* x = (const float*)d_in[0];
  const float* y = (const float*)d_in[1];
  float* out = (float*)d_out;

  char* ws = (char*)d_ws;
  __hip_bfloat16* zb = (__hip_bfloat16*)ws;                       // 4 MB
  float* rowsum  = (float*)(ws + (size_t)NROWS * DDIM * 2);       // 32 KB
  float* rowdiag = rowsum + NROWS;                                // 16 KB

  normalize_diag_kernel<<<1024, 256, 0, stream>>>(x, y, zb, rowdiag, rowsum);
  gram_lse_kernel<<<NBLK, 512, 0, stream>>>(zb, rowsum);
  finalize_kernel<<<1, 256, 0, stream>>>(rowsum, rowdiag, out);
}